// Round 5
// baseline (1940.214 us; speedup 1.0000x reference)
//
#include <hip/hip_runtime.h>
#include <hip/hip_fp16.h>
#include <stdint.h>

#define SEQ 512
#define HIDN 512

typedef _Float16 h2_t __attribute__((ext_vector_type(2)));
typedef _Float16 h8_t __attribute__((ext_vector_type(8)));
typedef float f4_t __attribute__((ext_vector_type(4)));

__device__ __forceinline__ float fdot2f(uint32_t a, uint32_t b, float c) {
#if __has_builtin(__builtin_amdgcn_fdot2)
  return __builtin_amdgcn_fdot2(__builtin_bit_cast(h2_t, a),
                                __builtin_bit_cast(h2_t, b), c, false);
#else
  h2_t ah = __builtin_bit_cast(h2_t, a);
  h2_t bh = __builtin_bit_cast(h2_t, b);
  return c + (float)ah.x * (float)bh.x + (float)ah.y * (float)bh.y;
#endif
}

// ---------------- fp32 -> fp16 convert (contiguous) ----------------
__global__ void k_cvt(const float4* __restrict__ src, __half2* __restrict__ dst, int n4) {
  int i = blockIdx.x * blockDim.x + threadIdx.x;
  if (i < n4) {
    float4 v = src[i];
    dst[2 * i]     = __floats2half2_rn(v.x, v.y);
    dst[2 * i + 1] = __floats2half2_rn(v.z, v.w);
  }
}

// ---------------- transpose + convert: dst[c][r] = (half)src[r][c] ----------------
__global__ void k_transpose_cvt(const float* __restrict__ src, __half* __restrict__ dst,
                                int R, int C) {
  __shared__ float tile[32][33];
  int tx = threadIdx.x, ty = threadIdx.y;
  int c0 = blockIdx.x * 32, r0 = blockIdx.y * 32;
#pragma unroll
  for (int i = 0; i < 4; ++i)
    tile[ty + i * 8][tx] = src[(size_t)(r0 + ty + i * 8) * C + c0 + tx];
  __syncthreads();
#pragma unroll
  for (int i = 0; i < 4; ++i)
    dst[(size_t)(c0 + ty + i * 8) * R + r0 + tx] = __float2half(tile[tx][ty + i * 8]);
}

// ---------------- f16 MFMA GEMM: C(MxN,f32) = A(MxK,f16) * Bt(NxK,f16)^T + bias ----------------
__global__ __launch_bounds__(256, 2) void k_gemm(
    const __half* __restrict__ A, const __half* __restrict__ Bt,
    const float* __restrict__ bias, float* __restrict__ C,
    int M, int N, int K) {
  __shared__ __align__(16) __half As[128 * 32];
  __shared__ __align__(16) __half Bs[128 * 32];
  const int tid = threadIdx.x;
  const int m0 = blockIdx.x * 128;
  const int n0 = blockIdx.y * 128;
  const int w = tid >> 6;
  const int lane = tid & 63;
  const int wm = (w >> 1) * 64;
  const int wn = (w & 1) * 64;
  const int fr = lane & 15;
  const int q = lane >> 4;
  const int lr = tid >> 2;
  const int lc = tid & 3;
  f4_t acc[4][4];
#pragma unroll
  for (int i = 0; i < 4; ++i)
#pragma unroll
    for (int jj = 0; jj < 4; ++jj) acc[i][jj] = (f4_t)(0.f);

  for (int kk = 0; kk < K; kk += 32) {
    *(uint4*)&As[lr * 32 + lc * 8]        = *(const uint4*)&A[(size_t)(m0 + lr) * K + kk + lc * 8];
    *(uint4*)&As[(64 + lr) * 32 + lc * 8] = *(const uint4*)&A[(size_t)(m0 + 64 + lr) * K + kk + lc * 8];
    *(uint4*)&Bs[lr * 32 + lc * 8]        = *(const uint4*)&Bt[(size_t)(n0 + lr) * K + kk + lc * 8];
    *(uint4*)&Bs[(64 + lr) * 32 + lc * 8] = *(const uint4*)&Bt[(size_t)(n0 + 64 + lr) * K + kk + lc * 8];
    __syncthreads();
    h8_t af[4], bf[4];
#pragma unroll
    for (int i = 0; i < 4; ++i) {
      af[i] = *(const h8_t*)&As[(wm + i * 16 + fr) * 32 + q * 8];
      bf[i] = *(const h8_t*)&Bs[(wn + i * 16 + fr) * 32 + q * 8];
    }
#pragma unroll
    for (int i = 0; i < 4; ++i)
#pragma unroll
      for (int jj = 0; jj < 4; ++jj)
        acc[i][jj] = __builtin_amdgcn_mfma_f32_16x16x32_f16(af[i], bf[jj], acc[i][jj], 0, 0, 0);
    __syncthreads();
  }
#pragma unroll
  for (int i = 0; i < 4; ++i) {
    const int row0 = m0 + wm + i * 16 + q * 4;
#pragma unroll
    for (int jj = 0; jj < 4; ++jj) {
      const int col = n0 + wn + jj * 16 + fr;
      const float bv = bias[col];
#pragma unroll
      for (int r = 0; r < 4; ++r)
        C[(size_t)(row0 + r) * N + col] = acc[i][jj][r] + bv;
    }
  }
}

// ---------------- serial recurrence: 64 blocks = (batch, direction) chains ----------------
// Lane j owns Wh column j: 180 f16-pairs register-resident + 76 pairs in LDS.
// Rounds 2-4 post-mortem: compiler SINKS the loop-invariant weight loads into the
// step loop (rematerialization heuristic; VGPR_Count stuck at 128, 12 TB of L2
// re-reads). Fix: pin each loaded dword with an empty `asm volatile "+v"` —
// volatile asm can't be sunk (execution count) and its result can't be remat'd,
// so the 180 values must stay live in VGPRs (budget 256 via waves_per_eu(2,2)).
#define REPEAT45(X) X(0) X(1) X(2) X(3) X(4) X(5) X(6) X(7) X(8) X(9) \
  X(10) X(11) X(12) X(13) X(14) X(15) X(16) X(17) X(18) X(19) \
  X(20) X(21) X(22) X(23) X(24) X(25) X(26) X(27) X(28) X(29) \
  X(30) X(31) X(32) X(33) X(34) X(35) X(36) X(37) X(38) X(39) \
  X(40) X(41) X(42) X(43) X(44)

__global__
__attribute__((amdgpu_flat_work_group_size(512, 512), amdgpu_waves_per_eu(2, 2)))
void k_rnn(
    const __half* __restrict__ WhT_f, const __half* __restrict__ WhT_b,
    const float* __restrict__ A_f, const float* __restrict__ A_b,
    __half* __restrict__ bi) {
  __shared__ uint32_t ldsw[76 * HIDN];          // 152 KB: pairs 180..255 of every column
  __shared__ __align__(16) __half hbuf[2][HIDN];
  const int j = threadIdx.x;
  const int d = blockIdx.x & 1;
  const int b = blockIdx.x >> 1;
  const __half* WhT = d ? WhT_b : WhT_f;        // WhT[j][k] = Wh[k][j]
  const float* A = (d ? A_b : A_f) + (size_t)b * SEQ * HIDN;
  __half* birow = bi + (size_t)b * SEQ * 1024 + d * HIDN + j;

  const uint4* wrow = (const uint4*)(WhT + (size_t)j * HIDN);
  const uint32_t* wrow32 = (const uint32_t*)wrow;

  // Load pairs 0..179 and PIN them in VGPRs (non-rematerializable defs).
#define DECLW(i) uint4 t##i = wrow[i]; \
  uint32_t w##i##0 = t##i.x, w##i##1 = t##i.y, w##i##2 = t##i.z, w##i##3 = t##i.w; \
  asm volatile("" : "+v"(w##i##0), "+v"(w##i##1), "+v"(w##i##2), "+v"(w##i##3));
  REPEAT45(DECLW)
#undef DECLW
#pragma unroll
  for (int p = 0; p < 76; ++p) ldsw[p * HIDN + j] = wrow32[180 + p];
  hbuf[0][j] = __float2half(0.f);
  __syncthreads();

  const int tstep = d ? -1 : 1;
  int t = d ? (SEQ - 1) : 0;
  float a_next = A[(size_t)t * HIDN + j];
  int cur = 0;
  for (int s = 0; s < SEQ; ++s) {
    float a_cur = a_next;
    int tn = t + tstep;
    tn = tn < 0 ? 0 : (tn > SEQ - 1 ? SEQ - 1 : tn);
    a_next = A[(size_t)tn * HIDN + j];          // prefetch next step's additive term
    const uint4* hp = (const uint4*)hbuf[cur];
    float acc0 = 0.f, acc1 = 0.f, acc2 = 0.f, acc3 = 0.f;
#define DOTW(i) { uint4 hv = hp[i]; \
    acc0 = fdot2f(hv.x, w##i##0, acc0); \
    acc1 = fdot2f(hv.y, w##i##1, acc1); \
    acc2 = fdot2f(hv.z, w##i##2, acc2); \
    acc3 = fdot2f(hv.w, w##i##3, acc3); }
    REPEAT45(DOTW)
#undef DOTW
#pragma unroll
    for (int g = 0; g < 19; ++g) {              // LDS-resident weights: pairs 180..255
      uint4 hv = hp[45 + g];
      acc0 = fdot2f(hv.x, ldsw[(g * 4 + 0) * HIDN + j], acc0);
      acc1 = fdot2f(hv.y, ldsw[(g * 4 + 1) * HIDN + j], acc1);
      acc2 = fdot2f(hv.z, ldsw[(g * 4 + 2) * HIDN + j], acc2);
      acc3 = fdot2f(hv.w, ldsw[(g * 4 + 3) * HIDN + j], acc3);
    }
    float p = a_cur + ((acc0 + acc1) + (acc2 + acc3));
    float ap = fabsf(p);
    float e = __expf(2.f * ap);
    float th = 1.f - 2.f * __builtin_amdgcn_rcpf(e + 1.f);  // tanh(|p|)
    float h = copysignf(th, p);
    __half hh = __float2half(h);
    hbuf[cur ^ 1][j] = hh;
    birow[(size_t)t * 1024] = hh;
    cur ^= 1;
    t += tstep;
    __syncthreads();
  }
}

extern "C" void kernel_launch(void* const* d_in, const int* in_sizes, int n_in,
                              void* d_out, int out_size, void* d_ws, size_t ws_size,
                              hipStream_t stream) {
  const float* input_seq = (const float*)d_in[0];  // (32,512,512)
  const float* W_f = (const float*)d_in[1];        // (1024,512)
  const float* b_f = (const float*)d_in[2];
  const float* W_b = (const float*)d_in[3];
  const float* b_b = (const float*)d_in[4];
  const float* W_o = (const float*)d_in[5];        // (1024,512)
  const float* b_o = (const float*)d_in[6];
  float* out = (float*)d_out;

  char* ws = (char*)d_ws;
  __half* Xh    = (__half*)(ws);                    // 16 MB  (16384x512 f16)
  float*  A_f   = (float*)(ws + 16777216);          // 32 MB
  float*  A_b   = (float*)(ws + 50331648);          // 32 MB
  __half* bi    = (__half*)(ws + 83886080);         // 32 MB  (16384x1024 f16)
  __half* WxT_f = (__half*)(ws + 117440512);        // 512 KB
  __half* WxT_b = (__half*)(ws + 117964800);
  __half* WhT_f = (__half*)(ws + 118489088);        // 512 KB
  __half* WhT_b = (__half*)(ws + 119013376);
  __half* WoT   = (__half*)(ws + 119537664);        // 1 MB

  k_cvt<<<8192, 256, 0, stream>>>((const float4*)input_seq, (__half2*)Xh, 2097152);
  dim3 tb(32, 8);
  k_transpose_cvt<<<dim3(16, 16), tb, 0, stream>>>(W_f,          WxT_f, 512, 512);
  k_transpose_cvt<<<dim3(16, 16), tb, 0, stream>>>(W_f + 262144, WhT_f, 512, 512);
  k_transpose_cvt<<<dim3(16, 16), tb, 0, stream>>>(W_b,          WxT_b, 512, 512);
  k_transpose_cvt<<<dim3(16, 16), tb, 0, stream>>>(W_b + 262144, WhT_b, 512, 512);
  k_transpose_cvt<<<dim3(16, 32), tb, 0, stream>>>(W_o,          WoT, 1024, 512);

  k_gemm<<<dim3(128, 4), 256, 0, stream>>>(Xh, WxT_f, b_f, A_f, 16384, 512, 512);
  k_gemm<<<dim3(128, 4), 256, 0, stream>>>(Xh, WxT_b, b_b, A_b, 16384, 512, 512);

  k_rnn<<<64, 512, 0, stream>>>(WhT_f, WhT_b, A_f, A_b, bi);

  k_gemm<<<dim3(128, 4), 256, 0, stream>>>(bi, WoT, b_o, out, 16384, 512, 1024);
}

// Round 6
// 998.507 us; speedup vs baseline: 1.9431x; 1.9431x over previous
//
#include <hip/hip_runtime.h>
#include <hip/hip_fp16.h>
#include <stdint.h>

#define SEQ 512
#define HIDN 512

typedef _Float16 h2_t __attribute__((ext_vector_type(2)));
typedef _Float16 h8_t __attribute__((ext_vector_type(8)));
typedef float f4_t __attribute__((ext_vector_type(4)));

__device__ __forceinline__ float fdot2f(uint32_t a, uint32_t b, float c) {
#if __has_builtin(__builtin_amdgcn_fdot2)
  return __builtin_amdgcn_fdot2(__builtin_bit_cast(h2_t, a),
                                __builtin_bit_cast(h2_t, b), c, false);
#else
  h2_t ah = __builtin_bit_cast(h2_t, a);
  h2_t bh = __builtin_bit_cast(h2_t, b);
  return c + (float)ah.x * (float)bh.x + (float)ah.y * (float)bh.y;
#endif
}

// ---------------- fp32 -> fp16 convert (contiguous) ----------------
__global__ void k_cvt(const float4* __restrict__ src, __half2* __restrict__ dst, int n4) {
  int i = blockIdx.x * blockDim.x + threadIdx.x;
  if (i < n4) {
    float4 v = src[i];
    dst[2 * i]     = __floats2half2_rn(v.x, v.y);
    dst[2 * i + 1] = __floats2half2_rn(v.z, v.w);
  }
}

// ---------------- transpose + convert: dst[c][r] = (half)src[r][c] ----------------
__global__ void k_transpose_cvt(const float* __restrict__ src, __half* __restrict__ dst,
                                int R, int C) {
  __shared__ float tile[32][33];
  int tx = threadIdx.x, ty = threadIdx.y;
  int c0 = blockIdx.x * 32, r0 = blockIdx.y * 32;
#pragma unroll
  for (int i = 0; i < 4; ++i)
    tile[ty + i * 8][tx] = src[(size_t)(r0 + ty + i * 8) * C + c0 + tx];
  __syncthreads();
#pragma unroll
  for (int i = 0; i < 4; ++i)
    dst[(size_t)(c0 + ty + i * 8) * R + r0 + tx] = __float2half(tile[tx][ty + i * 8]);
}

// ---------------- f16 MFMA GEMM: C(MxN,f32) = A(MxK,f16) * Bt(NxK,f16)^T + bias ----------------
__global__ __launch_bounds__(256, 2) void k_gemm(
    const __half* __restrict__ A, const __half* __restrict__ Bt,
    const float* __restrict__ bias, float* __restrict__ C,
    int M, int N, int K) {
  __shared__ __align__(16) __half As[128 * 32];
  __shared__ __align__(16) __half Bs[128 * 32];
  const int tid = threadIdx.x;
  const int m0 = blockIdx.x * 128;
  const int n0 = blockIdx.y * 128;
  const int w = tid >> 6;
  const int lane = tid & 63;
  const int wm = (w >> 1) * 64;
  const int wn = (w & 1) * 64;
  const int fr = lane & 15;
  const int q = lane >> 4;
  const int lr = tid >> 2;
  const int lc = tid & 3;
  f4_t acc[4][4];
#pragma unroll
  for (int i = 0; i < 4; ++i)
#pragma unroll
    for (int jj = 0; jj < 4; ++jj) acc[i][jj] = (f4_t)(0.f);

  for (int kk = 0; kk < K; kk += 32) {
    *(uint4*)&As[lr * 32 + lc * 8]        = *(const uint4*)&A[(size_t)(m0 + lr) * K + kk + lc * 8];
    *(uint4*)&As[(64 + lr) * 32 + lc * 8] = *(const uint4*)&A[(size_t)(m0 + 64 + lr) * K + kk + lc * 8];
    *(uint4*)&Bs[lr * 32 + lc * 8]        = *(const uint4*)&Bt[(size_t)(n0 + lr) * K + kk + lc * 8];
    *(uint4*)&Bs[(64 + lr) * 32 + lc * 8] = *(const uint4*)&Bt[(size_t)(n0 + 64 + lr) * K + kk + lc * 8];
    __syncthreads();
    h8_t af[4], bf[4];
#pragma unroll
    for (int i = 0; i < 4; ++i) {
      af[i] = *(const h8_t*)&As[(wm + i * 16 + fr) * 32 + q * 8];
      bf[i] = *(const h8_t*)&Bs[(wn + i * 16 + fr) * 32 + q * 8];
    }
#pragma unroll
    for (int i = 0; i < 4; ++i)
#pragma unroll
      for (int jj = 0; jj < 4; ++jj)
        acc[i][jj] = __builtin_amdgcn_mfma_f32_16x16x32_f16(af[i], bf[jj], acc[i][jj], 0, 0, 0);
    __syncthreads();
  }
#pragma unroll
  for (int i = 0; i < 4; ++i) {
    const int row0 = m0 + wm + i * 16 + q * 4;
#pragma unroll
    for (int jj = 0; jj < 4; ++jj) {
      const int col = n0 + wn + jj * 16 + fr;
      const float bv = bias[col];
#pragma unroll
      for (int r = 0; r < 4; ++r)
        C[(size_t)(row0 + r) * N + col] = acc[i][jj][r] + bv;
    }
  }
}

// ---------------- serial recurrence: 64 blocks x 1024 threads ----------------
// Rounds 2-5 lesson: the compiler caps k_rnn at 128 VGPRs no matter what; with
// 512-thr blocks our 180-reg plan was sunk (R3) or spilled (R5). New design
// ALIGNS with the cap: 1024 threads = 16 waves forces 4 waves/SIMD, whose
// hardware budget IS 128 regs (pool 512/SIMD) — allocator and HW agree.
// Thread (half,j) owns K-pairs [half*128, half*128+128) of column j:
//   92 pairs in regs (23 uint4, +~30 transients ~ 122 regs)
//   36 pairs in LDS as uint4 -> 9 ds_read_b128/thread/step (147 KB)
// Halves exchange partial dots via psum; 2 barriers/step. h broadcast via
// wave-uniform ds_read_b128 (~2 cyc each, calibrated from R2 counters).
__global__ __launch_bounds__(1024) void k_rnn(
    const __half* __restrict__ WhT_f, const __half* __restrict__ WhT_b,
    const float* __restrict__ A_f, const float* __restrict__ A_b,
    __half* __restrict__ bi) {
  __shared__ __align__(16) uint4 ldsw4[9 * 1024];   // 147456 B: pairs 92..127 of each half-column
  __shared__ __align__(16) __half hbuf[2][HIDN];    // 2 KB
  __shared__ float psum[2][HIDN];                   // 4 KB
  const int t = threadIdx.x;
  const int j = t & 511;
  const int half = t >> 9;
  const int d = blockIdx.x & 1;
  const int b = blockIdx.x >> 1;
  const __half* WhT = d ? WhT_b : WhT_f;            // WhT[j][k] = Wh[k][j]
  const float* A = (d ? A_b : A_f) + (size_t)b * SEQ * HIDN;
  __half* birow = bi + (size_t)b * SEQ * 1024 + d * HIDN + j;

  const uint4* wrow4 = (const uint4*)(WhT + (size_t)j * HIDN);  // 4 pairs per uint4
  uint4 wv[23];
#pragma unroll
  for (int i = 0; i < 23; ++i) wv[i] = wrow4[half * 32 + i];
#pragma unroll
  for (int p = 0; p < 9; ++p) ldsw4[p * 1024 + t] = wrow4[half * 32 + 23 + p];
  if (half == 0) hbuf[0][j] = __float2half(0.f);
  __syncthreads();

  const int tstep = d ? -1 : 1;
  int tt = d ? (SEQ - 1) : 0;
  float a_next = A[(size_t)tt * HIDN + j];
  int cur = 0;
  for (int s = 0; s < SEQ; ++s) {
    float a_cur = a_next;
    int tn = tt + tstep;
    tn = tn < 0 ? 0 : (tn > SEQ - 1 ? SEQ - 1 : tn);
    a_next = A[(size_t)tn * HIDN + j];              // prefetch next step's additive term
    // phase A: partial dot over this thread's 128 K-pairs
    const uint4* hp = (const uint4*)hbuf[cur] + half * 32;  // wave-uniform address
    float acc0 = 0.f, acc1 = 0.f, acc2 = 0.f, acc3 = 0.f;
#pragma unroll
    for (int i = 0; i < 23; ++i) {                  // register-resident weights
      uint4 hv = hp[i];
      acc0 = fdot2f(hv.x, wv[i].x, acc0);
      acc1 = fdot2f(hv.y, wv[i].y, acc1);
      acc2 = fdot2f(hv.z, wv[i].z, acc2);
      acc3 = fdot2f(hv.w, wv[i].w, acc3);
    }
#pragma unroll
    for (int p = 0; p < 9; ++p) {                   // LDS-resident weights (b128 reads)
      uint4 hv = hp[23 + p];
      uint4 lw = ldsw4[p * 1024 + t];
      acc0 = fdot2f(hv.x, lw.x, acc0);
      acc1 = fdot2f(hv.y, lw.y, acc1);
      acc2 = fdot2f(hv.z, lw.z, acc2);
      acc3 = fdot2f(hv.w, lw.w, acc3);
    }
    psum[half][j] = (acc0 + acc1) + (acc2 + acc3);
    __syncthreads();
    // phase B: combine halves, tanh, publish h (both halves compute redundantly)
    float p = psum[0][j] + psum[1][j] + a_cur;
    float ap = fabsf(p);
    float e = __expf(2.f * ap);
    float th = 1.f - 2.f * __builtin_amdgcn_rcpf(e + 1.f);  // tanh(|p|)
    float h = copysignf(th, p);
    __half hh = __float2half(h);
    hbuf[cur ^ 1][j] = hh;                          // both halves write same value (benign)
    if (half == 0) birow[(size_t)tt * 1024] = hh;   // wave-uniform branch
    cur ^= 1;
    tt += tstep;
    __syncthreads();
  }
}

extern "C" void kernel_launch(void* const* d_in, const int* in_sizes, int n_in,
                              void* d_out, int out_size, void* d_ws, size_t ws_size,
                              hipStream_t stream) {
  const float* input_seq = (const float*)d_in[0];  // (32,512,512)
  const float* W_f = (const float*)d_in[1];        // (1024,512)
  const float* b_f = (const float*)d_in[2];
  const float* W_b = (const float*)d_in[3];
  const float* b_b = (const float*)d_in[4];
  const float* W_o = (const float*)d_in[5];        // (1024,512)
  const float* b_o = (const float*)d_in[6];
  float* out = (float*)d_out;

  char* ws = (char*)d_ws;
  __half* Xh    = (__half*)(ws);                    // 16 MB  (16384x512 f16)
  float*  A_f   = (float*)(ws + 16777216);          // 32 MB
  float*  A_b   = (float*)(ws + 50331648);          // 32 MB
  __half* bi    = (__half*)(ws + 83886080);         // 32 MB  (16384x1024 f16)
  __half* WxT_f = (__half*)(ws + 117440512);        // 512 KB
  __half* WxT_b = (__half*)(ws + 117964800);
  __half* WhT_f = (__half*)(ws + 118489088);        // 512 KB
  __half* WhT_b = (__half*)(ws + 119013376);
  __half* WoT   = (__half*)(ws + 119537664);        // 1 MB

  k_cvt<<<8192, 256, 0, stream>>>((const float4*)input_seq, (__half2*)Xh, 2097152);
  dim3 tb(32, 8);
  k_transpose_cvt<<<dim3(16, 16), tb, 0, stream>>>(W_f,          WxT_f, 512, 512);
  k_transpose_cvt<<<dim3(16, 16), tb, 0, stream>>>(W_f + 262144, WhT_f, 512, 512);
  k_transpose_cvt<<<dim3(16, 16), tb, 0, stream>>>(W_b,          WxT_b, 512, 512);
  k_transpose_cvt<<<dim3(16, 16), tb, 0, stream>>>(W_b + 262144, WhT_b, 512, 512);
  k_transpose_cvt<<<dim3(16, 32), tb, 0, stream>>>(W_o,          WoT, 1024, 512);

  k_gemm<<<dim3(128, 4), 256, 0, stream>>>(Xh, WxT_f, b_f, A_f, 16384, 512, 512);
  k_gemm<<<dim3(128, 4), 256, 0, stream>>>(Xh, WxT_b, b_b, A_b, 16384, 512, 512);

  k_rnn<<<64, 1024, 0, stream>>>(WhT_f, WhT_b, A_f, A_b, bi);

  k_gemm<<<dim3(128, 4), 256, 0, stream>>>(bi, WoT, b_o, out, 16384, 512, 1024);
}